// Round 8
// baseline (1148.934 us; speedup 1.0000x reference)
//
#include <hip/hip_runtime.h>
#include <math.h>

constexpr int NN = 100000;   // nodes
constexpr int NE = 1600000;  // edges
constexpr int H  = 128;      // feat/hidden
constexpr int NG = 100;      // graphs
constexpr int NC = 10;       // classes
constexpr int NB = 98;       // CSR buckets (dst >> 10)
constexpr int NCHUNK = 13;   // src chunks (src >> 13)
constexpr int NSLOT = 64;    // stats partial slots

typedef _Float16 half8 __attribute__((ext_vector_type(8)));
typedef _Float16 half4 __attribute__((ext_vector_type(4)));
typedef float    f32x4 __attribute__((ext_vector_type(4)));

// ---------------- degree (int) ----------------
__global__ void k_deg(const int* __restrict__ dst, int* __restrict__ deg) {
    int e = blockIdx.x * 256 + threadIdx.x;
    if (e < NE) atomicAdd(&deg[dst[e]], 1);
}

// ---------------- scan pass 1 (+ dis = rsqrt(deg+1) fused) ----------------
__global__ __launch_bounds__(256) void k_scan1(const int* __restrict__ deg, int* __restrict__ out,
                                               int* __restrict__ partials, float* __restrict__ dis) {
    __shared__ int tsum[256];
    int base = blockIdx.x * 1024;
    int tid = threadIdx.x;
    int v[4]; int s = 0;
    #pragma unroll
    for (int k = 0; k < 4; k++) {
        int i = base + tid * 4 + k;
        v[k] = (i < NN) ? deg[i] : 0;
        if (i < NN) dis[i] = rsqrtf((float)v[k] + 1.0f);
        s += v[k];
    }
    tsum[tid] = s;
    __syncthreads();
    for (int off = 1; off < 256; off <<= 1) {
        int t = (tid >= off) ? tsum[tid - off] : 0;
        __syncthreads();
        tsum[tid] += t;
        __syncthreads();
    }
    int run = (tid == 0) ? 0 : tsum[tid - 1];
    #pragma unroll
    for (int k = 0; k < 4; k++) {
        int i = base + tid * 4 + k;
        if (i < NN) out[i] = run;
        run += v[k];
    }
    if (tid == 255) partials[blockIdx.x] = tsum[255];
}

// ---------------- scan pass 2 (block 0) + graph boundaries (block 1) ----------------
__global__ void k_scan2g(int* __restrict__ partials, int nb,
                         const int* __restrict__ batch, int* __restrict__ gstart) {
    int tid = threadIdx.x;
    if (blockIdx.x == 0) {
        __shared__ int s[128];
        s[tid] = (tid < nb) ? partials[tid] : 0;
        __syncthreads();
        if (tid == 0) { int run = 0; for (int i = 0; i < nb; i++) { int t = s[i]; s[i] = run; run += t; } }
        __syncthreads();
        if (tid < nb) partials[tid] = s[tid];
    } else {
        int g = tid;
        if (g > NG) return;
        if (g == NG) { gstart[g] = NN; return; }
        int lo = 0, hi = NN;
        while (lo < hi) { int mid = (lo + hi) >> 1; if (batch[mid] < g) lo = mid + 1; else hi = mid; }
        gstart[g] = lo;
    }
}

// ---------------- scan pass 3 (+ bucket cursor init fused) ----------------
__global__ void k_scan3(int* __restrict__ rowptr, const int* __restrict__ partials,
                        int* __restrict__ cursor, int* __restrict__ bcur) {
    int i = blockIdx.x * 256 + threadIdx.x;
    if (i < NN) {
        int v = rowptr[i] + partials[i >> 10];
        rowptr[i] = v;
        cursor[i] = v;
        if ((i & 1023) == 0) bcur[i >> 10] = v;
    }
    if (i == 0) rowptr[NN] = NE;
}

// ---------------- CSR build pass 1: bin edges into 1024-node dst buckets ----------------
__global__ __launch_bounds__(256) void k_bucket1(const int* __restrict__ src,
                                                 const int* __restrict__ dst,
                                                 int* __restrict__ bcur,
                                                 int2* __restrict__ staging) {
    __shared__ int hist[NB];
    __shared__ int base[NB];
    int tid = threadIdx.x;
    int chunk0 = blockIdx.x * 8192;
    if (tid < NB) hist[tid] = 0;
    __syncthreads();
    for (int i = tid; i < 8192; i += 256) {
        int e = chunk0 + i;
        if (e < NE) atomicAdd(&hist[dst[e] >> 10], 1);
    }
    __syncthreads();
    if (tid < NB) { base[tid] = atomicAdd(&bcur[tid], hist[tid]); hist[tid] = 0; }
    __syncthreads();
    for (int i = tid; i < 8192; i += 256) {
        int e = chunk0 + i;
        if (e < NE) {
            int d = dst[e];
            int b = d >> 10;
            int off = atomicAdd(&hist[b], 1);
            staging[base[b] + off] = make_int2(src[e], d);
        }
    }
}

// ---------------- CSR build pass 2: bucket-local scatter, src-chunk-major order ----------------
// Rows owned by (dst&3); 13 passes over L2-hot staging so each row's cols come out
// grouped by ascending src chunk -> k_agg gathers sweep a ~2MB window (L2 locality).
__global__ __launch_bounds__(256) void k_bucket2(const int2* __restrict__ staging,
                                                 const int* __restrict__ rowptr,
                                                 int* __restrict__ cursor,
                                                 int* __restrict__ col) {
    int b = blockIdx.x >> 2, own = blockIdx.x & 3;
    int nend = (b + 1) << 10; if (nend > NN) nend = NN;
    int s0 = rowptr[b << 10], s1 = rowptr[nend];
    for (int chunk = 0; chunk < NCHUNK; chunk++) {
        for (int i = s0 + threadIdx.x; i < s1; i += 256) {
            int2 e = staging[i];
            if ((e.y & 3) == own && (e.x >> 13) == chunk) {
                int pos = atomicAdd(&cursor[e.y], 1);
                col[pos] = e.x;
            }
        }
        __syncthreads();
    }
}

// ---------------- W -> Wt (transposed, f16), all 3 layers, one dispatch ----------------
__global__ void k_prepw3(const float* __restrict__ W0, const float* __restrict__ W1,
                         const float* __restrict__ W2, _Float16* __restrict__ Wt) {
    int gi = blockIdx.x * 256 + threadIdx.x;  // 3 * 16384
    int l = gi >> 14, idx = gi & 16383;
    const float* W = (l == 0) ? W0 : (l == 1) ? W1 : W2;
    int n = idx >> 7, k = idx & 127;
    Wt[gi] = (_Float16)W[k * 128 + n];
}

// ---------------- MFMA GEMM: Y_f16 = (relu(X*scale+shift) @ W) * dis[row] ----------------
__global__ __launch_bounds__(256) void k_gemm(const float* __restrict__ Xf,
                                              const _Float16* __restrict__ Xh,
                                              const float* __restrict__ ss,
                                              const _Float16* __restrict__ Wt,
                                              const float* __restrict__ dis,
                                              _Float16* __restrict__ Y) {
    __shared__ _Float16 Wl[128][136];
    __shared__ _Float16 Xl[64][136];
    int tid = threadIdx.x;
    int row0 = blockIdx.x * 64;

    #pragma unroll
    for (int p = 0; p < 8; p++) {
        int idx = p * 2048 + tid * 8;
        int r = idx >> 7, c = idx & 127;
        *(uint4*)&Wl[r][c] = ((const uint4*)Wt)[idx >> 3];
    }
    if (Xh) {
        #pragma unroll
        for (int p = 0; p < 4; p++) {
            int idx = p * 2048 + tid * 8;
            int r = idx >> 7, c = idx & 127;
            int gr = row0 + r;
            half8 hv = {};
            if (gr < NN) hv = *(const half8*)&Xh[(size_t)gr * H + c];
            float4 sc0 = ((const float4*)ss)[c >> 2];
            float4 sc1 = ((const float4*)ss)[(c >> 2) + 1];
            float4 sh0 = ((const float4*)(ss + 128))[c >> 2];
            float4 sh1 = ((const float4*)(ss + 128))[(c >> 2) + 1];
            half8 o;
            o[0] = (_Float16)fmaxf((float)hv[0] * sc0.x + sh0.x, 0.f);
            o[1] = (_Float16)fmaxf((float)hv[1] * sc0.y + sh0.y, 0.f);
            o[2] = (_Float16)fmaxf((float)hv[2] * sc0.z + sh0.z, 0.f);
            o[3] = (_Float16)fmaxf((float)hv[3] * sc0.w + sh0.w, 0.f);
            o[4] = (_Float16)fmaxf((float)hv[4] * sc1.x + sh1.x, 0.f);
            o[5] = (_Float16)fmaxf((float)hv[5] * sc1.y + sh1.y, 0.f);
            o[6] = (_Float16)fmaxf((float)hv[6] * sc1.z + sh1.z, 0.f);
            o[7] = (_Float16)fmaxf((float)hv[7] * sc1.w + sh1.w, 0.f);
            *(half8*)&Xl[r][c] = o;
        }
    } else {
        #pragma unroll
        for (int p = 0; p < 8; p++) {
            int idx = p * 1024 + tid * 4;
            int r = idx >> 7, c = idx & 127;
            int gr = row0 + r;
            float4 v = make_float4(0.f, 0.f, 0.f, 0.f);
            if (gr < NN) v = *(const float4*)&Xf[(size_t)gr * H + c];
            half4 hv = {(_Float16)v.x, (_Float16)v.y, (_Float16)v.z, (_Float16)v.w};
            *(half4*)&Xl[r][c] = hv;
        }
    }
    __syncthreads();

    int wave = tid >> 6;
    int lane = tid & 63;
    int m = lane & 15;
    int quad = lane >> 4;

    half8 afrag[4];
    #pragma unroll
    for (int kc = 0; kc < 4; kc++)
        afrag[kc] = *(const half8*)&Xl[wave * 16 + m][kc * 32 + quad * 8];

    f32x4 acc[8];
    #pragma unroll
    for (int nt = 0; nt < 8; nt++) acc[nt] = (f32x4){0.f, 0.f, 0.f, 0.f};

    #pragma unroll
    for (int kc = 0; kc < 4; kc++) {
        #pragma unroll
        for (int nt = 0; nt < 8; nt++) {
            half8 b = *(const half8*)&Wl[nt * 16 + m][kc * 32 + quad * 8];
            acc[nt] = __builtin_amdgcn_mfma_f32_16x16x32_f16(afrag[kc], b, acc[nt], 0, 0, 0);
        }
    }

    float dv[4];
    #pragma unroll
    for (int r = 0; r < 4; r++) {
        int gr = row0 + wave * 16 + quad * 4 + r;
        dv[r] = (gr < NN) ? dis[gr] : 0.f;
    }
    #pragma unroll
    for (int nt = 0; nt < 8; nt++) {
        int c = nt * 16 + m;
        #pragma unroll
        for (int r = 0; r < 4; r++) {
            int gr = row0 + wave * 16 + quad * 4 + r;
            if (gr < NN) Y[(size_t)gr * H + c] = (_Float16)(acc[nt][r] * dv[r]);
        }
    }
}

// ---------------- gather aggregate + fused BN-stats partials ----------------
// out = dis[d]*(h'[d] + sum h'[col]) + bias   (h' pre-scaled by dis)
// Block-level column sum/sumsq reduced in LDS, atomically added to sp[slot].
__global__ __launch_bounds__(256) void k_agg(const _Float16* __restrict__ hs,
                                             const int* __restrict__ rowptr,
                                             const int* __restrict__ col,
                                             const float* __restrict__ dis,
                                             const float* __restrict__ bias,
                                             _Float16* __restrict__ out,
                                             float* __restrict__ sp) {
    int node = blockIdx.x * 8 + (threadIdx.x >> 5);
    int lane = threadIdx.x & 31;
    int grp = threadIdx.x >> 5;
    int beg = rowptr[node], end = rowptr[node + 1];
    float dd = dis[node];
    const half4* h4 = (const half4*)hs;
    half4 a = h4[(size_t)node * 32 + lane];
    float4 acc = make_float4((float)a.x, (float)a.y, (float)a.z, (float)a.w);
    int j = beg;
    for (; j + 8 <= end; j += 8) {
        int c[8];
        #pragma unroll
        for (int u = 0; u < 8; u++) c[u] = col[j + u];
        half4 v[8];
        #pragma unroll
        for (int u = 0; u < 8; u++) v[u] = h4[(size_t)c[u] * 32 + lane];
        #pragma unroll
        for (int u = 0; u < 8; u++) {
            acc.x += (float)v[u].x; acc.y += (float)v[u].y;
            acc.z += (float)v[u].z; acc.w += (float)v[u].w;
        }
    }
    for (; j + 2 <= end; j += 2) {
        int c0 = col[j], c1 = col[j + 1];
        half4 v0 = h4[(size_t)c0 * 32 + lane];
        half4 v1 = h4[(size_t)c1 * 32 + lane];
        acc.x += (float)v0.x + (float)v1.x; acc.y += (float)v0.y + (float)v1.y;
        acc.z += (float)v0.z + (float)v1.z; acc.w += (float)v0.w + (float)v1.w;
    }
    if (j < end) {
        half4 v = h4[(size_t)col[j] * 32 + lane];
        acc.x += (float)v.x; acc.y += (float)v.y;
        acc.z += (float)v.z; acc.w += (float)v.w;
    }
    float4 bb = ((const float4*)bias)[lane];
    float4 o = make_float4(acc.x * dd + bb.x, acc.y * dd + bb.y,
                           acc.z * dd + bb.z, acc.w * dd + bb.w);
    half4 oh = {(_Float16)o.x, (_Float16)o.y, (_Float16)o.z, (_Float16)o.w};
    ((half4*)out)[(size_t)node * 32 + lane] = oh;

    // BN stats partials (on f32 values, pre-rounding)
    __shared__ float4 lsum[8][32];
    __shared__ float4 lsq[8][32];
    lsum[grp][lane] = o;
    lsq[grp][lane] = make_float4(o.x * o.x, o.y * o.y, o.z * o.z, o.w * o.w);
    __syncthreads();
    int t = threadIdx.x;
    int c = t & 127;         // column
    int which = t >> 7;      // 0 = sum, 1 = sumsq
    float v = 0.f;
    #pragma unroll
    for (int r = 0; r < 8; r++) {
        float4 q = which ? lsq[r][c >> 2] : lsum[r][c >> 2];
        v += (c & 3) == 0 ? q.x : (c & 3) == 1 ? q.y : (c & 3) == 2 ? q.z : q.w;
    }
    atomicAdd(&sp[(blockIdx.x & (NSLOT - 1)) * 256 + which * 128 + c], v);
}

// ---------------- BN stats final reduce + scale/shift (re-zeros sp for next layer) ----------------
__global__ __launch_bounds__(256) void k_stats_bss(float* __restrict__ sp,
                                                   const float* __restrict__ gamma,
                                                   const float* __restrict__ beta,
                                                   float* __restrict__ ss) {
    __shared__ float sums[256];
    int c = threadIdx.x;  // 256
    float a = 0.f;
    for (int i = 0; i < NSLOT; i++) { a += sp[i * 256 + c]; sp[i * 256 + c] = 0.f; }
    sums[c] = a;
    __syncthreads();
    if (c < 128) {
        float mean = sums[c] * (1.0f / NN);
        float var  = sums[128 + c] * (1.0f / NN) - mean * mean;
        float sc   = gamma[c] * rsqrtf(var + 1e-5f);
        ss[c] = sc;
        ss[128 + c] = beta[c] - mean * sc;
    }
}

// ---------------- mean pool with fused BN+ReLU ----------------
__global__ __launch_bounds__(256) void k_pool2(const _Float16* __restrict__ x,
                                               const float* __restrict__ ss,
                                               const int* __restrict__ gstart,
                                               float* __restrict__ pooled) {
    int g = blockIdx.x;
    int beg = gstart[g], end = gstart[g + 1];
    int lane = threadIdx.x & 31;
    int walker = threadIdx.x >> 5;
    const half4* x4 = (const half4*)x;
    float4 sc = ((const float4*)ss)[lane];
    float4 sh = ((const float4*)(ss + 128))[lane];
    float4 acc = make_float4(0.f, 0.f, 0.f, 0.f);
    for (int r = beg + walker; r < end; r += 8) {
        half4 v = x4[(size_t)r * 32 + lane];
        acc.x += fmaxf((float)v.x * sc.x + sh.x, 0.f);
        acc.y += fmaxf((float)v.y * sc.y + sh.y, 0.f);
        acc.z += fmaxf((float)v.z * sc.z + sh.z, 0.f);
        acc.w += fmaxf((float)v.w * sc.w + sh.w, 0.f);
    }
    __shared__ float4 red[256];
    red[threadIdx.x] = acc;
    __syncthreads();
    if (threadIdx.x < 32) {
        float4 s = red[threadIdx.x];
        for (int w = 1; w < 8; w++) {
            float4 v = red[w * 32 + threadIdx.x];
            s.x += v.x; s.y += v.y; s.z += v.z; s.w += v.w;
        }
        float inv = 1.0f / fmaxf((float)(end - beg), 1.0f);
        ((float4*)pooled)[g * 32 + threadIdx.x] =
            make_float4(s.x * inv, s.y * inv, s.z * inv, s.w * inv);
    }
}

// ---------------- MLP head + log_softmax ----------------
__global__ __launch_bounds__(128) void k_head(const float* __restrict__ pooled,
                                              const float* __restrict__ w1, const float* __restrict__ b1,
                                              const float* __restrict__ w2, const float* __restrict__ b2,
                                              float* __restrict__ out) {
    __shared__ float p[H], hh[H], lg[NC], red;
    int g = blockIdx.x, f = threadIdx.x;
    p[f] = pooled[g * H + f];
    __syncthreads();
    float a = b1[f];
    for (int k = 0; k < H; k++) a += p[k] * w1[k * H + f];
    hh[f] = a > 0.f ? a : 0.f;
    __syncthreads();
    if (f < NC) {
        float l = b2[f];
        for (int k = 0; k < H; k++) l += hh[k] * w2[k * NC + f];
        lg[f] = l;
    }
    __syncthreads();
    if (f == 0) {
        float m = lg[0];
        for (int c = 1; c < NC; c++) m = m > lg[c] ? m : lg[c];
        float s = 0.f;
        for (int c = 0; c < NC; c++) s += expf(lg[c] - m);
        red = m + logf(s);
    }
    __syncthreads();
    if (f < NC) out[g * NC + f] = lg[f] - red;
}

extern "C" void kernel_launch(void* const* d_in, const int* in_sizes, int n_in,
                              void* d_out, int out_size, void* d_ws, size_t ws_size,
                              hipStream_t stream) {
    const float* x     = (const float*)d_in[0];
    const int*   ei    = (const int*)d_in[1];
    const int*   srcp  = ei;
    const int*   dstp  = ei + NE;
    const int*   batch = (const int*)d_in[2];
    const float* W[3]  = {(const float*)d_in[3],  (const float*)d_in[7],  (const float*)d_in[11]};
    const float* b[3]  = {(const float*)d_in[4],  (const float*)d_in[8],  (const float*)d_in[12]};
    const float* gm[3] = {(const float*)d_in[5],  (const float*)d_in[9],  (const float*)d_in[13]};
    const float* bt[3] = {(const float*)d_in[6],  (const float*)d_in[10], (const float*)d_in[14]};
    const float* w1 = (const float*)d_in[15];
    const float* b1 = (const float*)d_in[16];
    const float* w2 = (const float*)d_in[17];
    const float* b2 = (const float*)d_in[18];
    float* out = (float*)d_out;

    float* ws        = (float*)d_ws;
    float* dis       = ws;                          // 100000
    int*   deg_i     = (int*)(ws + 100000);         // 100000 (doubles as cursor)
    int*   rowptr    = (int*)(ws + 200000);         // 100004
    int*   partials  = (int*)(ws + 300004);         // 128
    int*   gstart    = (int*)(ws + 300132);         // 104
    int*   bcur      = (int*)(ws + 300236);         // 128
    float* ssbuf     = ws + 300364;                 // 768
    float* pooled    = ws + 301132;                 // 12800
    float* sp        = ws + 313932;                 // NSLOT*256 = 16384
    _Float16* wt     = (_Float16*)(ws + 330316);    // 3*16384 halves
    int*   col       = (int*)(ws + 354892);         // NE
    int2*  staging   = (int2*)(ws + 1954892);       // NE int2
    _Float16* aggh   = (_Float16*)(ws + 5154892);   // NN*H f16
    _Float16* hb     = (_Float16*)(ws + 11554892);  // NN*H f16

    const int nScanBlocks = (NN + 1023) / 1024;  // 98

    hipMemsetAsync(deg_i, 0, NN * sizeof(int), stream);
    hipMemsetAsync(sp, 0, NSLOT * 256 * sizeof(float), stream);
    k_deg<<<(NE + 255) / 256, 256, 0, stream>>>(dstp, deg_i);
    k_scan1<<<nScanBlocks, 256, 0, stream>>>(deg_i, rowptr, partials, dis);
    k_scan2g<<<2, 128, 0, stream>>>(partials, nScanBlocks, batch, gstart);
    k_scan3<<<(NN + 255) / 256, 256, 0, stream>>>(rowptr, partials, deg_i /*cursor*/, bcur);
    k_bucket1<<<(NE + 8191) / 8192, 256, 0, stream>>>(srcp, dstp, bcur, staging);
    k_bucket2<<<NB * 4, 256, 0, stream>>>(staging, rowptr, deg_i, col);
    k_prepw3<<<192, 256, 0, stream>>>(W[0], W[1], W[2], wt);

    const float* ss_prev = nullptr;
    for (int l = 0; l < 3; l++) {
        float* ss = ssbuf + l * 256;
        k_gemm<<<(NN + 63) / 64, 256, 0, stream>>>(l == 0 ? x : nullptr,
                                                   l == 0 ? nullptr : aggh,
                                                   ss_prev, wt + l * 16384, dis, hb);
        k_agg<<<NN / 8, 256, 0, stream>>>(hb, rowptr, col, dis, b[l], aggh, sp);
        k_stats_bss<<<1, 256, 0, stream>>>(sp, gm[l], bt[l], ss);
        ss_prev = ss;
    }

    k_pool2<<<NG, 256, 0, stream>>>(aggh, ssbuf + 2 * 256, gstart, pooled);
    k_head<<<NG, 128, 0, stream>>>(pooled, w1, b1, w2, b2, out);
}

// Round 9
// 770.715 us; speedup vs baseline: 1.4907x; 1.4907x over previous
//
#include <hip/hip_runtime.h>
#include <hip/hip_fp8.h>
#include <math.h>

constexpr int NN = 100000;   // nodes
constexpr int NE = 1600000;  // edges
constexpr int H  = 128;      // feat/hidden
constexpr int NG = 100;      // graphs
constexpr int NC = 10;       // classes
constexpr int NB = 98;       // CSR buckets (dst >> 10)

typedef _Float16 half8 __attribute__((ext_vector_type(8)));
typedef _Float16 half4 __attribute__((ext_vector_type(4)));
typedef float    f32x4 __attribute__((ext_vector_type(4)));
typedef float    f32x2 __attribute__((ext_vector_type(2)));

// ---- fp8 e4m3 (OCP) helpers ----
static __device__ __forceinline__ unsigned char ftofp8(float f) {
#if __has_builtin(__builtin_amdgcn_cvt_pk_fp8_f32)
    int r = __builtin_amdgcn_cvt_pk_fp8_f32(f, f, 0, false);
    return (unsigned char)(r & 0xff);
#else
    __hip_fp8_e4m3 v(f);
    unsigned char b; __builtin_memcpy(&b, &v, 1); return b;
#endif
}

static __device__ __forceinline__ float4 fp8x4tof(unsigned int u) {
#if __has_builtin(__builtin_amdgcn_cvt_pk_f32_fp8)
    f32x2 lo = __builtin_amdgcn_cvt_pk_f32_fp8(u, false);
    f32x2 hi = __builtin_amdgcn_cvt_pk_f32_fp8(u, true);
    return make_float4(lo.x, lo.y, hi.x, hi.y);
#else
    float r[4];
    #pragma unroll
    for (int i = 0; i < 4; i++) {
        unsigned char b = (u >> (8 * i)) & 0xff;
        __hip_fp8_e4m3 v; __builtin_memcpy(&v, &b, 1); r[i] = (float)v;
    }
    return make_float4(r[0], r[1], r[2], r[3]);
#endif
}

// ---------------- degree (int) ----------------
__global__ void k_deg(const int* __restrict__ dst, int* __restrict__ deg) {
    int e = blockIdx.x * 256 + threadIdx.x;
    if (e < NE) atomicAdd(&deg[dst[e]], 1);
}

// ---------------- scan pass 1 (+ dis = rsqrt(deg+1) fused) ----------------
__global__ __launch_bounds__(256) void k_scan1(const int* __restrict__ deg, int* __restrict__ out,
                                               int* __restrict__ partials, float* __restrict__ dis) {
    __shared__ int tsum[256];
    int base = blockIdx.x * 1024;
    int tid = threadIdx.x;
    int v[4]; int s = 0;
    #pragma unroll
    for (int k = 0; k < 4; k++) {
        int i = base + tid * 4 + k;
        v[k] = (i < NN) ? deg[i] : 0;
        if (i < NN) dis[i] = rsqrtf((float)v[k] + 1.0f);
        s += v[k];
    }
    tsum[tid] = s;
    __syncthreads();
    for (int off = 1; off < 256; off <<= 1) {
        int t = (tid >= off) ? tsum[tid - off] : 0;
        __syncthreads();
        tsum[tid] += t;
        __syncthreads();
    }
    int run = (tid == 0) ? 0 : tsum[tid - 1];
    #pragma unroll
    for (int k = 0; k < 4; k++) {
        int i = base + tid * 4 + k;
        if (i < NN) out[i] = run;
        run += v[k];
    }
    if (tid == 255) partials[blockIdx.x] = tsum[255];
}

// ---------------- scan pass 2 (block 0) + graph boundaries (block 1) ----------------
__global__ void k_scan2g(int* __restrict__ partials, int nb,
                         const int* __restrict__ batch, int* __restrict__ gstart) {
    int tid = threadIdx.x;
    if (blockIdx.x == 0) {
        __shared__ int s[128];
        s[tid] = (tid < nb) ? partials[tid] : 0;
        __syncthreads();
        if (tid == 0) { int run = 0; for (int i = 0; i < nb; i++) { int t = s[i]; s[i] = run; run += t; } }
        __syncthreads();
        if (tid < nb) partials[tid] = s[tid];
    } else {
        int g = tid;
        if (g > NG) return;
        if (g == NG) { gstart[g] = NN; return; }
        int lo = 0, hi = NN;
        while (lo < hi) { int mid = (lo + hi) >> 1; if (batch[mid] < g) lo = mid + 1; else hi = mid; }
        gstart[g] = lo;
    }
}

// ---------------- scan pass 3 (+ bucket cursor init fused) ----------------
__global__ void k_scan3(int* __restrict__ rowptr, const int* __restrict__ partials,
                        int* __restrict__ cursor, int* __restrict__ bcur) {
    int i = blockIdx.x * 256 + threadIdx.x;
    if (i < NN) {
        int v = rowptr[i] + partials[i >> 10];
        rowptr[i] = v;
        cursor[i] = v;
        if ((i & 1023) == 0) bcur[i >> 10] = v;
    }
    if (i == 0) rowptr[NN] = NE;
}

// ---------------- CSR build pass 1: bin edges into 1024-node dst buckets ----------------
__global__ __launch_bounds__(256) void k_bucket1(const int* __restrict__ src,
                                                 const int* __restrict__ dst,
                                                 int* __restrict__ bcur,
                                                 int2* __restrict__ staging) {
    __shared__ int hist[NB];
    __shared__ int base[NB];
    int tid = threadIdx.x;
    int chunk0 = blockIdx.x * 8192;
    if (tid < NB) hist[tid] = 0;
    __syncthreads();
    for (int i = tid; i < 8192; i += 256) {
        int e = chunk0 + i;
        if (e < NE) atomicAdd(&hist[dst[e] >> 10], 1);
    }
    __syncthreads();
    if (tid < NB) { base[tid] = atomicAdd(&bcur[tid], hist[tid]); hist[tid] = 0; }
    __syncthreads();
    for (int i = tid; i < 8192; i += 256) {
        int e = chunk0 + i;
        if (e < NE) {
            int d = dst[e];
            int b = d >> 10;
            int off = atomicAdd(&hist[b], 1);
            staging[base[b] + off] = make_int2(src[e], d);
        }
    }
}

// ---------------- CSR build pass 2: bucket-local scatter (R7 version) ----------------
__global__ __launch_bounds__(256) void k_bucket2(const int2* __restrict__ staging,
                                                 const int* __restrict__ rowptr,
                                                 int* __restrict__ cursor,
                                                 int* __restrict__ col) {
    int b = blockIdx.x >> 2, q = blockIdx.x & 3;
    int nend = (b + 1) << 10; if (nend > NN) nend = NN;
    int s0 = rowptr[b << 10], s1 = rowptr[nend];
    for (int i = s0 + q * 256 + threadIdx.x; i < s1; i += 1024) {
        int2 e = staging[i];
        int pos = atomicAdd(&cursor[e.y], 1);
        col[pos] = e.x;
    }
}

// ---------------- W -> Wt (transposed, f16), all 3 layers, one dispatch ----------------
__global__ void k_prepw3(const float* __restrict__ W0, const float* __restrict__ W1,
                         const float* __restrict__ W2, _Float16* __restrict__ Wt) {
    int gi = blockIdx.x * 256 + threadIdx.x;  // 3 * 16384
    int l = gi >> 14, idx = gi & 16383;
    const float* W = (l == 0) ? W0 : (l == 1) ? W1 : W2;
    int n = idx >> 7, k = idx & 127;
    Wt[gi] = (_Float16)W[k * 128 + n];
}

// ---------------- MFMA GEMM: Y_fp8 = (relu(X*scale+shift) @ W) * dis[row] ----------------
__global__ __launch_bounds__(256) void k_gemm(const float* __restrict__ Xf,
                                              const _Float16* __restrict__ Xh,
                                              const float* __restrict__ ss,
                                              const _Float16* __restrict__ Wt,
                                              const float* __restrict__ dis,
                                              unsigned char* __restrict__ Y) {
    __shared__ _Float16 Wl[128][136];
    __shared__ _Float16 Xl[64][136];
    int tid = threadIdx.x;
    int row0 = blockIdx.x * 64;

    #pragma unroll
    for (int p = 0; p < 8; p++) {
        int idx = p * 2048 + tid * 8;
        int r = idx >> 7, c = idx & 127;
        *(uint4*)&Wl[r][c] = ((const uint4*)Wt)[idx >> 3];
    }
    if (Xh) {
        #pragma unroll
        for (int p = 0; p < 4; p++) {
            int idx = p * 2048 + tid * 8;
            int r = idx >> 7, c = idx & 127;
            int gr = row0 + r;
            half8 hv = {};
            if (gr < NN) hv = *(const half8*)&Xh[(size_t)gr * H + c];
            float4 sc0 = ((const float4*)ss)[c >> 2];
            float4 sc1 = ((const float4*)ss)[(c >> 2) + 1];
            float4 sh0 = ((const float4*)(ss + 128))[c >> 2];
            float4 sh1 = ((const float4*)(ss + 128))[(c >> 2) + 1];
            half8 o;
            o[0] = (_Float16)fmaxf((float)hv[0] * sc0.x + sh0.x, 0.f);
            o[1] = (_Float16)fmaxf((float)hv[1] * sc0.y + sh0.y, 0.f);
            o[2] = (_Float16)fmaxf((float)hv[2] * sc0.z + sh0.z, 0.f);
            o[3] = (_Float16)fmaxf((float)hv[3] * sc0.w + sh0.w, 0.f);
            o[4] = (_Float16)fmaxf((float)hv[4] * sc1.x + sh1.x, 0.f);
            o[5] = (_Float16)fmaxf((float)hv[5] * sc1.y + sh1.y, 0.f);
            o[6] = (_Float16)fmaxf((float)hv[6] * sc1.z + sh1.z, 0.f);
            o[7] = (_Float16)fmaxf((float)hv[7] * sc1.w + sh1.w, 0.f);
            *(half8*)&Xl[r][c] = o;
        }
    } else {
        #pragma unroll
        for (int p = 0; p < 8; p++) {
            int idx = p * 1024 + tid * 4;
            int r = idx >> 7, c = idx & 127;
            int gr = row0 + r;
            float4 v = make_float4(0.f, 0.f, 0.f, 0.f);
            if (gr < NN) v = *(const float4*)&Xf[(size_t)gr * H + c];
            half4 hv = {(_Float16)v.x, (_Float16)v.y, (_Float16)v.z, (_Float16)v.w};
            *(half4*)&Xl[r][c] = hv;
        }
    }
    __syncthreads();

    int wave = tid >> 6;
    int lane = tid & 63;
    int m = lane & 15;
    int quad = lane >> 4;

    half8 afrag[4];
    #pragma unroll
    for (int kc = 0; kc < 4; kc++)
        afrag[kc] = *(const half8*)&Xl[wave * 16 + m][kc * 32 + quad * 8];

    f32x4 acc[8];
    #pragma unroll
    for (int nt = 0; nt < 8; nt++) acc[nt] = (f32x4){0.f, 0.f, 0.f, 0.f};

    #pragma unroll
    for (int kc = 0; kc < 4; kc++) {
        #pragma unroll
        for (int nt = 0; nt < 8; nt++) {
            half8 b = *(const half8*)&Wl[nt * 16 + m][kc * 32 + quad * 8];
            acc[nt] = __builtin_amdgcn_mfma_f32_16x16x32_f16(afrag[kc], b, acc[nt], 0, 0, 0);
        }
    }

    float dv[4];
    #pragma unroll
    for (int r = 0; r < 4; r++) {
        int gr = row0 + wave * 16 + quad * 4 + r;
        dv[r] = (gr < NN) ? dis[gr] : 0.f;
    }
    #pragma unroll
    for (int nt = 0; nt < 8; nt++) {
        int c = nt * 16 + m;
        #pragma unroll
        for (int r = 0; r < 4; r++) {
            int gr = row0 + wave * 16 + quad * 4 + r;
            if (gr < NN) Y[(size_t)gr * H + c] = ftofp8(acc[nt][r] * dv[r]);
        }
    }
}

// ---------------- gather aggregate: out = dis[d]*(h'[d] + sum h'[col]) + bias ----------------
// h' is fp8 e4m3, pre-scaled by dis. Unroll x8 for memory-level parallelism.
__global__ __launch_bounds__(256) void k_agg(const unsigned char* __restrict__ hs,
                                             const int* __restrict__ rowptr,
                                             const int* __restrict__ col,
                                             const float* __restrict__ dis,
                                             const float* __restrict__ bias,
                                             _Float16* __restrict__ out) {
    int node = blockIdx.x * 8 + (threadIdx.x >> 5);
    int lane = threadIdx.x & 31;
    int beg = rowptr[node], end = rowptr[node + 1];
    float dd = dis[node];
    const unsigned int* h4 = (const unsigned int*)hs;  // 32 dwords per row
    float4 sv = fp8x4tof(h4[(size_t)node * 32 + lane]);
    float4 acc = sv;
    int j = beg;
    for (; j + 8 <= end; j += 8) {
        int c[8];
        #pragma unroll
        for (int u = 0; u < 8; u++) c[u] = col[j + u];
        unsigned int w[8];
        #pragma unroll
        for (int u = 0; u < 8; u++) w[u] = h4[(size_t)c[u] * 32 + lane];
        #pragma unroll
        for (int u = 0; u < 8; u++) {
            float4 v = fp8x4tof(w[u]);
            acc.x += v.x; acc.y += v.y; acc.z += v.z; acc.w += v.w;
        }
    }
    for (; j + 2 <= end; j += 2) {
        unsigned int w0 = h4[(size_t)col[j] * 32 + lane];
        unsigned int w1 = h4[(size_t)col[j + 1] * 32 + lane];
        float4 v0 = fp8x4tof(w0), v1 = fp8x4tof(w1);
        acc.x += v0.x + v1.x; acc.y += v0.y + v1.y;
        acc.z += v0.z + v1.z; acc.w += v0.w + v1.w;
    }
    if (j < end) {
        float4 v = fp8x4tof(h4[(size_t)col[j] * 32 + lane]);
        acc.x += v.x; acc.y += v.y; acc.z += v.z; acc.w += v.w;
    }
    float4 bb = ((const float4*)bias)[lane];
    half4 o = {(_Float16)(acc.x * dd + bb.x), (_Float16)(acc.y * dd + bb.y),
               (_Float16)(acc.z * dd + bb.z), (_Float16)(acc.w * dd + bb.w)};
    ((half4*)out)[(size_t)node * 32 + lane] = o;
}

// ---------------- BN stats stage a ----------------
__global__ __launch_bounds__(128) void k_stats_a(const _Float16* __restrict__ x,
                                                 float* __restrict__ part) {
    int blk = blockIdx.x;  // 512 blocks x 196 rows
    int f = threadIdx.x;   // 128
    int r0 = blk * 196, r1 = r0 + 196 < NN ? r0 + 196 : NN;
    float s = 0.f, s2 = 0.f;
    for (int r = r0; r < r1; r++) {
        float v = (float)x[(size_t)r * H + f];
        s += v; s2 += v * v;
    }
    part[blk * 256 + f] = s;
    part[blk * 256 + 128 + f] = s2;
}

// ---------------- BN stats stage b + scale/shift, fused ----------------
__global__ __launch_bounds__(256) void k_stats_bss(const float* __restrict__ part,
                                                   const float* __restrict__ gamma,
                                                   const float* __restrict__ beta,
                                                   float* __restrict__ ss) {
    __shared__ float sums[256];
    int c = threadIdx.x;  // 256
    float a = 0.f;
    for (int i = 0; i < 512; i++) a += part[i * 256 + c];
    sums[c] = a;
    __syncthreads();
    if (c < 128) {
        float mean = sums[c] * (1.0f / NN);
        float var  = sums[128 + c] * (1.0f / NN) - mean * mean;
        float sc   = gamma[c] * rsqrtf(var + 1e-5f);
        ss[c] = sc;
        ss[128 + c] = beta[c] - mean * sc;
    }
}

// ---------------- fused mean pool (BN+ReLU) + MLP head + log_softmax ----------------
__global__ __launch_bounds__(256) void k_poolhead(const _Float16* __restrict__ x,
                                                  const float* __restrict__ ss,
                                                  const int* __restrict__ gstart,
                                                  const float* __restrict__ w1, const float* __restrict__ b1,
                                                  const float* __restrict__ w2, const float* __restrict__ b2,
                                                  float* __restrict__ out) {
    int g = blockIdx.x;
    int beg = gstart[g], end = gstart[g + 1];
    int lane = threadIdx.x & 31;
    int walker = threadIdx.x >> 5;
    const half4* x4 = (const half4*)x;
    float4 sc = ((const float4*)ss)[lane];
    float4 sh = ((const float4*)(ss + 128))[lane];
    float4 acc = make_float4(0.f, 0.f, 0.f, 0.f);
    for (int r = beg + walker; r < end; r += 8) {
        half4 v = x4[(size_t)r * 32 + lane];
        acc.x += fmaxf((float)v.x * sc.x + sh.x, 0.f);
        acc.y += fmaxf((float)v.y * sc.y + sh.y, 0.f);
        acc.z += fmaxf((float)v.z * sc.z + sh.z, 0.f);
        acc.w += fmaxf((float)v.w * sc.w + sh.w, 0.f);
    }
    __shared__ float4 red[256];
    __shared__ float p[H], hh[H], lg[NC], lsred;
    red[threadIdx.x] = acc;
    __syncthreads();
    if (threadIdx.x < 32) {
        float4 s = red[threadIdx.x];
        for (int w = 1; w < 8; w++) {
            float4 v = red[w * 32 + threadIdx.x];
            s.x += v.x; s.y += v.y; s.z += v.z; s.w += v.w;
        }
        float inv = 1.0f / fmaxf((float)(end - beg), 1.0f);
        ((float4*)p)[threadIdx.x] = make_float4(s.x * inv, s.y * inv, s.z * inv, s.w * inv);
    }
    __syncthreads();
    int f = threadIdx.x;
    if (f < H) {
        float a = b1[f];
        for (int k = 0; k < H; k++) a += p[k] * w1[k * H + f];
        hh[f] = a > 0.f ? a : 0.f;
    }
    __syncthreads();
    if (f < NC) {
        float l = b2[f];
        for (int k = 0; k < H; k++) l += hh[k] * w2[k * NC + f];
        lg[f] = l;
    }
    __syncthreads();
    if (f == 0) {
        float m = lg[0];
        for (int c = 1; c < NC; c++) m = m > lg[c] ? m : lg[c];
        float s = 0.f;
        for (int c = 0; c < NC; c++) s += expf(lg[c] - m);
        lsred = m + logf(s);
    }
    __syncthreads();
    if (f < NC) out[g * NC + f] = lg[f] - lsred;
}

extern "C" void kernel_launch(void* const* d_in, const int* in_sizes, int n_in,
                              void* d_out, int out_size, void* d_ws, size_t ws_size,
                              hipStream_t stream) {
    const float* x     = (const float*)d_in[0];
    const int*   ei    = (const int*)d_in[1];
    const int*   srcp  = ei;
    const int*   dstp  = ei + NE;
    const int*   batch = (const int*)d_in[2];
    const float* W[3]  = {(const float*)d_in[3],  (const float*)d_in[7],  (const float*)d_in[11]};
    const float* b[3]  = {(const float*)d_in[4],  (const float*)d_in[8],  (const float*)d_in[12]};
    const float* gm[3] = {(const float*)d_in[5],  (const float*)d_in[9],  (const float*)d_in[13]};
    const float* bt[3] = {(const float*)d_in[6],  (const float*)d_in[10], (const float*)d_in[14]};
    const float* w1 = (const float*)d_in[15];
    const float* b1 = (const float*)d_in[16];
    const float* w2 = (const float*)d_in[17];
    const float* b2 = (const float*)d_in[18];
    float* out = (float*)d_out;

    float* ws        = (float*)d_ws;
    float* dis       = ws;                          // 100000
    int*   deg_i     = (int*)(ws + 100000);         // 100000 (doubles as cursor)
    int*   rowptr    = (int*)(ws + 200000);         // 100004
    int*   partials  = (int*)(ws + 300004);         // 128
    int*   gstart    = (int*)(ws + 300132);         // 104
    int*   bcur      = (int*)(ws + 300236);         // 128
    float* ssbuf     = ws + 300364;                 // 768
    float* sp        = ws + 301132;                 // 131072 (stats partials)
    _Float16* wt     = (_Float16*)(ws + 432204);    // 3*16384 halves = 24576 floats
    int*   col       = (int*)(ws + 456780);         // NE
    int2*  staging   = (int2*)(ws + 2056780);       // NE int2
    _Float16* aggh   = (_Float16*)(ws + 5256780);   // NN*H f16
    unsigned char* hb = (unsigned char*)(ws + 11656780);  // NN*H fp8

    const int nScanBlocks = (NN + 1023) / 1024;  // 98

    hipMemsetAsync(deg_i, 0, NN * sizeof(int), stream);
    k_deg<<<(NE + 255) / 256, 256, 0, stream>>>(dstp, deg_i);
    k_scan1<<<nScanBlocks, 256, 0, stream>>>(deg_i, rowptr, partials, dis);
    k_scan2g<<<2, 128, 0, stream>>>(partials, nScanBlocks, batch, gstart);
    k_scan3<<<(NN + 255) / 256, 256, 0, stream>>>(rowptr, partials, deg_i /*cursor*/, bcur);
    k_bucket1<<<(NE + 8191) / 8192, 256, 0, stream>>>(srcp, dstp, bcur, staging);
    k_bucket2<<<NB * 4, 256, 0, stream>>>(staging, rowptr, deg_i, col);
    k_prepw3<<<192, 256, 0, stream>>>(W[0], W[1], W[2], wt);

    const float* ss_prev = nullptr;
    for (int l = 0; l < 3; l++) {
        float* ss = ssbuf + l * 256;
        k_gemm<<<(NN + 63) / 64, 256, 0, stream>>>(l == 0 ? x : nullptr,
                                                   l == 0 ? nullptr : aggh,
                                                   ss_prev, wt + l * 16384, dis, hb);
        k_agg<<<NN / 8, 256, 0, stream>>>(hb, rowptr, col, dis, b[l], aggh);
        k_stats_a<<<512, 128, 0, stream>>>(aggh, sp);
        k_stats_bss<<<1, 256, 0, stream>>>(sp, gm[l], bt[l], ss);
        ss_prev = ss;
    }

    k_poolhead<<<NG, 256, 0, stream>>>(aggh, ssbuf + 2 * 256, gstart, w1, b1, w2, b2, out);
}

// Round 10
// 699.198 us; speedup vs baseline: 1.6432x; 1.1023x over previous
//
#include <hip/hip_runtime.h>
#include <hip/hip_fp8.h>
#include <math.h>

constexpr int NN = 100000;   // nodes
constexpr int NE = 1600000;  // edges
constexpr int H  = 128;      // feat/hidden
constexpr int NG = 100;      // graphs
constexpr int NC = 10;       // classes
constexpr int NB = 98;       // CSR buckets (dst >> 10)
constexpr int CAP = 18432;   // per-bucket staging capacity (mean 16327, +16 sigma)

typedef _Float16 half8 __attribute__((ext_vector_type(8)));
typedef _Float16 half4 __attribute__((ext_vector_type(4)));
typedef float    f32x4 __attribute__((ext_vector_type(4)));
typedef float    f32x2 __attribute__((ext_vector_type(2)));

// ---- fp8 e4m3 (OCP) helpers ----
static __device__ __forceinline__ unsigned char ftofp8(float f) {
#if __has_builtin(__builtin_amdgcn_cvt_pk_fp8_f32)
    int r = __builtin_amdgcn_cvt_pk_fp8_f32(f, f, 0, false);
    return (unsigned char)(r & 0xff);
#else
    __hip_fp8_e4m3 v(f);
    unsigned char b; __builtin_memcpy(&b, &v, 1); return b;
#endif
}

static __device__ __forceinline__ float4 fp8x4tof(unsigned int u) {
#if __has_builtin(__builtin_amdgcn_cvt_pk_f32_fp8)
    f32x2 lo = __builtin_amdgcn_cvt_pk_f32_fp8(u, false);
    f32x2 hi = __builtin_amdgcn_cvt_pk_f32_fp8(u, true);
    return make_float4(lo.x, lo.y, hi.x, hi.y);
#else
    float r[4];
    #pragma unroll
    for (int i = 0; i < 4; i++) {
        unsigned char b = (u >> (8 * i)) & 0xff;
        __hip_fp8_e4m3 v; __builtin_memcpy(&v, &b, 1); r[i] = (float)v;
    }
    return make_float4(r[0], r[1], r[2], r[3]);
#endif
}

// ---------------- CSR build pass 1: bin edges into fixed-CAP dst-bucket regions ----------------
__global__ __launch_bounds__(256) void k_bucket1(const int* __restrict__ src,
                                                 const int* __restrict__ dst,
                                                 int* __restrict__ bcnt,
                                                 int2* __restrict__ staging) {
    __shared__ int hist[NB];
    __shared__ int base[NB];
    int tid = threadIdx.x;
    int chunk0 = blockIdx.x * 8192;
    if (tid < NB) hist[tid] = 0;
    __syncthreads();
    for (int i = tid; i < 8192; i += 256) {
        int e = chunk0 + i;
        if (e < NE) atomicAdd(&hist[dst[e] >> 10], 1);
    }
    __syncthreads();
    if (tid < NB) { base[tid] = atomicAdd(&bcnt[tid], hist[tid]); hist[tid] = 0; }
    __syncthreads();
    for (int i = tid; i < 8192; i += 256) {
        int e = chunk0 + i;
        if (e < NE) {
            int d = dst[e];
            int bk = d >> 10;
            int off = base[bk] + atomicAdd(&hist[bk], 1);
            if (off < CAP) staging[(size_t)bk * CAP + off] = make_int2(src[e], d);
        }
    }
}

// ---------------- bucket prefix (block 0) + graph boundaries (block 1) ----------------
__global__ void k_bprefix(const int* __restrict__ bcnt, int* __restrict__ bbase,
                          int* __restrict__ rowptr,
                          const int* __restrict__ batch, int* __restrict__ gstart) {
    if (blockIdx.x == 0) {
        if (threadIdx.x == 0) {
            int run = 0;
            for (int i = 0; i < NB; i++) { bbase[i] = run; run += bcnt[i]; }
            rowptr[NN] = NE;
        }
    } else {
        int g = threadIdx.x;
        if (g > NG) return;
        if (g == NG) { gstart[g] = NN; return; }
        int lo = 0, hi = NN;
        while (lo < hi) { int mid = (lo + hi) >> 1; if (batch[mid] < g) lo = mid + 1; else hi = mid; }
        gstart[g] = lo;
    }
}

// ---------------- CSR build pass 2: per-bucket deg/rowptr/dis + col scatter, all in LDS ----------------
__global__ __launch_bounds__(256) void k_bucket2(const int2* __restrict__ staging,
                                                 const int* __restrict__ bcnt,
                                                 const int* __restrict__ bbase,
                                                 int* __restrict__ rowptr,
                                                 float* __restrict__ dis,
                                                 int* __restrict__ col) {
    __shared__ int degl[1024];
    __shared__ int cur[1024];
    __shared__ int tsum[256];
    int b = blockIdx.x, tid = threadIdx.x;
    int n0 = b << 10;
    int cnt = bcnt[b];
    int base = bbase[b];
    const int2* st = staging + (size_t)b * CAP;
    ((int4*)degl)[tid] = make_int4(0, 0, 0, 0);
    __syncthreads();
    for (int i = tid; i < cnt; i += 256) atomicAdd(&degl[st[i].y - n0], 1);
    __syncthreads();
    int v[4], s = 0;
    #pragma unroll
    for (int k = 0; k < 4; k++) { v[k] = degl[tid * 4 + k]; s += v[k]; }
    tsum[tid] = s;
    __syncthreads();
    for (int off = 1; off < 256; off <<= 1) {
        int t = (tid >= off) ? tsum[tid - off] : 0;
        __syncthreads();
        tsum[tid] += t;
        __syncthreads();
    }
    int run = (tid == 0) ? 0 : tsum[tid - 1];
    #pragma unroll
    for (int k = 0; k < 4; k++) {
        int i = tid * 4 + k, node = n0 + i;
        if (node < NN) {
            rowptr[node] = base + run;
            cur[i] = run;
            dis[node] = rsqrtf((float)v[k] + 1.0f);
        }
        run += v[k];
    }
    __syncthreads();
    for (int i = tid; i < cnt; i += 256) {
        int2 e = st[i];
        int pos = atomicAdd(&cur[e.y - n0], 1);
        col[base + pos] = e.x;
    }
}

// ---------------- W -> Wt (transposed, f16), all 3 layers, one dispatch ----------------
__global__ void k_prepw3(const float* __restrict__ W0, const float* __restrict__ W1,
                         const float* __restrict__ W2, _Float16* __restrict__ Wt) {
    int gi = blockIdx.x * 256 + threadIdx.x;  // 3 * 16384
    int l = gi >> 14, idx = gi & 16383;
    const float* W = (l == 0) ? W0 : (l == 1) ? W1 : W2;
    int n = idx >> 7, k = idx & 127;
    Wt[gi] = (_Float16)W[k * 128 + n];
}

// ---------------- MFMA GEMM: Y_fp8 = (relu(X*scale+shift) @ W) * dis[row] ----------------
__global__ __launch_bounds__(256) void k_gemm(const float* __restrict__ Xf,
                                              const _Float16* __restrict__ Xh,
                                              const float* __restrict__ ss,
                                              const _Float16* __restrict__ Wt,
                                              const float* __restrict__ dis,
                                              unsigned char* __restrict__ Y) {
    __shared__ _Float16 Wl[128][136];
    __shared__ _Float16 Xl[64][136];
    int tid = threadIdx.x;
    int row0 = blockIdx.x * 64;

    #pragma unroll
    for (int p = 0; p < 8; p++) {
        int idx = p * 2048 + tid * 8;
        int r = idx >> 7, c = idx & 127;
        *(uint4*)&Wl[r][c] = ((const uint4*)Wt)[idx >> 3];
    }
    if (Xh) {
        #pragma unroll
        for (int p = 0; p < 4; p++) {
            int idx = p * 2048 + tid * 8;
            int r = idx >> 7, c = idx & 127;
            int gr = row0 + r;
            half8 hv = {};
            if (gr < NN) hv = *(const half8*)&Xh[(size_t)gr * H + c];
            float4 sc0 = ((const float4*)ss)[c >> 2];
            float4 sc1 = ((const float4*)ss)[(c >> 2) + 1];
            float4 sh0 = ((const float4*)(ss + 128))[c >> 2];
            float4 sh1 = ((const float4*)(ss + 128))[(c >> 2) + 1];
            half8 o;
            o[0] = (_Float16)fmaxf((float)hv[0] * sc0.x + sh0.x, 0.f);
            o[1] = (_Float16)fmaxf((float)hv[1] * sc0.y + sh0.y, 0.f);
            o[2] = (_Float16)fmaxf((float)hv[2] * sc0.z + sh0.z, 0.f);
            o[3] = (_Float16)fmaxf((float)hv[3] * sc0.w + sh0.w, 0.f);
            o[4] = (_Float16)fmaxf((float)hv[4] * sc1.x + sh1.x, 0.f);
            o[5] = (_Float16)fmaxf((float)hv[5] * sc1.y + sh1.y, 0.f);
            o[6] = (_Float16)fmaxf((float)hv[6] * sc1.z + sh1.z, 0.f);
            o[7] = (_Float16)fmaxf((float)hv[7] * sc1.w + sh1.w, 0.f);
            *(half8*)&Xl[r][c] = o;
        }
    } else {
        #pragma unroll
        for (int p = 0; p < 8; p++) {
            int idx = p * 1024 + tid * 4;
            int r = idx >> 7, c = idx & 127;
            int gr = row0 + r;
            float4 v = make_float4(0.f, 0.f, 0.f, 0.f);
            if (gr < NN) v = *(const float4*)&Xf[(size_t)gr * H + c];
            half4 hv = {(_Float16)v.x, (_Float16)v.y, (_Float16)v.z, (_Float16)v.w};
            *(half4*)&Xl[r][c] = hv;
        }
    }
    __syncthreads();

    int wave = tid >> 6;
    int lane = tid & 63;
    int m = lane & 15;
    int quad = lane >> 4;

    half8 afrag[4];
    #pragma unroll
    for (int kc = 0; kc < 4; kc++)
        afrag[kc] = *(const half8*)&Xl[wave * 16 + m][kc * 32 + quad * 8];

    f32x4 acc[8];
    #pragma unroll
    for (int nt = 0; nt < 8; nt++) acc[nt] = (f32x4){0.f, 0.f, 0.f, 0.f};

    #pragma unroll
    for (int kc = 0; kc < 4; kc++) {
        #pragma unroll
        for (int nt = 0; nt < 8; nt++) {
            half8 b = *(const half8*)&Wl[nt * 16 + m][kc * 32 + quad * 8];
            acc[nt] = __builtin_amdgcn_mfma_f32_16x16x32_f16(afrag[kc], b, acc[nt], 0, 0, 0);
        }
    }

    float dv[4];
    #pragma unroll
    for (int r = 0; r < 4; r++) {
        int gr = row0 + wave * 16 + quad * 4 + r;
        dv[r] = (gr < NN) ? dis[gr] : 0.f;
    }
    #pragma unroll
    for (int nt = 0; nt < 8; nt++) {
        int c = nt * 16 + m;
        #pragma unroll
        for (int r = 0; r < 4; r++) {
            int gr = row0 + wave * 16 + quad * 4 + r;
            if (gr < NN) Y[(size_t)gr * H + c] = ftofp8(acc[nt][r] * dv[r]);
        }
    }
}

// ---------------- gather aggregate: out = dis[d]*(h'[d] + sum h'[col]) + bias ----------------
// fp8 rows = 128B. 8 lanes x dwordx4 per row; 4 edge sub-streams per 32-lane group
// (4 edges per VMEM instruction), unroll 4 -> 16 edges in flight. shfl_xor cross-sub reduce.
__global__ __launch_bounds__(256) void k_agg(const unsigned char* __restrict__ hs,
                                             const int* __restrict__ rowptr,
                                             const int* __restrict__ col,
                                             const float* __restrict__ dis,
                                             const float* __restrict__ bias,
                                             _Float16* __restrict__ out) {
    int node = blockIdx.x * 8 + (threadIdx.x >> 5);
    int lane = threadIdx.x & 31;
    int fl = lane & 7;     // feature slice: features 16*fl .. 16*fl+15
    int sub = lane >> 3;   // edge sub-stream 0..3
    int beg = rowptr[node], end = rowptr[node + 1];
    float dd = dis[node];
    const uint4* h16 = (const uint4*)hs;  // 8 uint4 per row

    float acc[16];
    #pragma unroll
    for (int k = 0; k < 16; k++) acc[k] = 0.f;
    if (sub == 0) {
        uint4 w = h16[(size_t)node * 8 + fl];
        float4 a0 = fp8x4tof(w.x), a1 = fp8x4tof(w.y), a2 = fp8x4tof(w.z), a3 = fp8x4tof(w.w);
        acc[0] = a0.x; acc[1] = a0.y; acc[2] = a0.z; acc[3] = a0.w;
        acc[4] = a1.x; acc[5] = a1.y; acc[6] = a1.z; acc[7] = a1.w;
        acc[8] = a2.x; acc[9] = a2.y; acc[10] = a2.z; acc[11] = a2.w;
        acc[12] = a3.x; acc[13] = a3.y; acc[14] = a3.z; acc[15] = a3.w;
    }

    #define ACCUM(W) { \
        float4 t0 = fp8x4tof((W).x), t1 = fp8x4tof((W).y), t2 = fp8x4tof((W).z), t3 = fp8x4tof((W).w); \
        acc[0] += t0.x; acc[1] += t0.y; acc[2] += t0.z; acc[3] += t0.w; \
        acc[4] += t1.x; acc[5] += t1.y; acc[6] += t1.z; acc[7] += t1.w; \
        acc[8] += t2.x; acc[9] += t2.y; acc[10] += t2.z; acc[11] += t2.w; \
        acc[12] += t3.x; acc[13] += t3.y; acc[14] += t3.z; acc[15] += t3.w; }

    int j = beg + sub;
    for (; j + 12 < end; j += 16) {
        int c0 = col[j], c1 = col[j + 4], c2 = col[j + 8], c3 = col[j + 12];
        uint4 w0 = h16[(size_t)c0 * 8 + fl];
        uint4 w1 = h16[(size_t)c1 * 8 + fl];
        uint4 w2 = h16[(size_t)c2 * 8 + fl];
        uint4 w3 = h16[(size_t)c3 * 8 + fl];
        ACCUM(w0) ACCUM(w1) ACCUM(w2) ACCUM(w3)
    }
    for (; j < end; j += 4) {
        uint4 w = h16[(size_t)col[j] * 8 + fl];
        ACCUM(w)
    }
    #undef ACCUM

    // combine the 4 sub-streams (xor 8 and 16 stay inside the 32-lane group)
    #pragma unroll
    for (int k = 0; k < 16; k++) {
        acc[k] += __shfl_xor(acc[k], 8, 64);
        acc[k] += __shfl_xor(acc[k], 16, 64);
    }

    if (sub == 0) {
        float4 b0 = ((const float4*)bias)[fl * 4 + 0];
        float4 b1 = ((const float4*)bias)[fl * 4 + 1];
        float4 b2 = ((const float4*)bias)[fl * 4 + 2];
        float4 b3 = ((const float4*)bias)[fl * 4 + 3];
        half8 o0, o1;
        o0[0] = (_Float16)(acc[0] * dd + b0.x); o0[1] = (_Float16)(acc[1] * dd + b0.y);
        o0[2] = (_Float16)(acc[2] * dd + b0.z); o0[3] = (_Float16)(acc[3] * dd + b0.w);
        o0[4] = (_Float16)(acc[4] * dd + b1.x); o0[5] = (_Float16)(acc[5] * dd + b1.y);
        o0[6] = (_Float16)(acc[6] * dd + b1.z); o0[7] = (_Float16)(acc[7] * dd + b1.w);
        o1[0] = (_Float16)(acc[8] * dd + b2.x); o1[1] = (_Float16)(acc[9] * dd + b2.y);
        o1[2] = (_Float16)(acc[10] * dd + b2.z); o1[3] = (_Float16)(acc[11] * dd + b2.w);
        o1[4] = (_Float16)(acc[12] * dd + b3.x); o1[5] = (_Float16)(acc[13] * dd + b3.y);
        o1[6] = (_Float16)(acc[14] * dd + b3.z); o1[7] = (_Float16)(acc[15] * dd + b3.w);
        half8* orow = (half8*)(out + (size_t)node * H);
        orow[fl * 2] = o0;
        orow[fl * 2 + 1] = o1;
    }
}

// ---------------- BN stats stage a ----------------
__global__ __launch_bounds__(128) void k_stats_a(const _Float16* __restrict__ x,
                                                 float* __restrict__ part) {
    int blk = blockIdx.x;  // 512 blocks x 196 rows
    int f = threadIdx.x;   // 128
    int r0 = blk * 196, r1 = r0 + 196 < NN ? r0 + 196 : NN;
    float s = 0.f, s2 = 0.f;
    for (int r = r0; r < r1; r++) {
        float v = (float)x[(size_t)r * H + f];
        s += v; s2 += v * v;
    }
    part[blk * 256 + f] = s;
    part[blk * 256 + 128 + f] = s2;
}

// ---------------- BN stats stage b + scale/shift, fused ----------------
__global__ __launch_bounds__(256) void k_stats_bss(const float* __restrict__ part,
                                                   const float* __restrict__ gamma,
                                                   const float* __restrict__ beta,
                                                   float* __restrict__ ss) {
    __shared__ float sums[256];
    int c = threadIdx.x;  // 256
    float a = 0.f;
    for (int i = 0; i < 512; i++) a += part[i * 256 + c];
    sums[c] = a;
    __syncthreads();
    if (c < 128) {
        float mean = sums[c] * (1.0f / NN);
        float var  = sums[128 + c] * (1.0f / NN) - mean * mean;
        float sc   = gamma[c] * rsqrtf(var + 1e-5f);
        ss[c] = sc;
        ss[128 + c] = beta[c] - mean * sc;
    }
}

// ---------------- fused mean pool (BN+ReLU) + MLP head + log_softmax ----------------
__global__ __launch_bounds__(256) void k_poolhead(const _Float16* __restrict__ x,
                                                  const float* __restrict__ ss,
                                                  const int* __restrict__ gstart,
                                                  const float* __restrict__ w1, const float* __restrict__ b1,
                                                  const float* __restrict__ w2, const float* __restrict__ b2,
                                                  float* __restrict__ out) {
    int g = blockIdx.x;
    int beg = gstart[g], end = gstart[g + 1];
    int lane = threadIdx.x & 31;
    int walker = threadIdx.x >> 5;
    const half4* x4 = (const half4*)x;
    float4 sc = ((const float4*)ss)[lane];
    float4 sh = ((const float4*)(ss + 128))[lane];
    float4 acc = make_float4(0.f, 0.f, 0.f, 0.f);
    for (int r = beg + walker; r < end; r += 8) {
        half4 v = x4[(size_t)r * 32 + lane];
        acc.x += fmaxf((float)v.x * sc.x + sh.x, 0.f);
        acc.y += fmaxf((float)v.y * sc.y + sh.y, 0.f);
        acc.z += fmaxf((float)v.z * sc.z + sh.z, 0.f);
        acc.w += fmaxf((float)v.w * sc.w + sh.w, 0.f);
    }
    __shared__ float4 red[256];
    __shared__ float p[H], hh[H], lg[NC], lsred;
    red[threadIdx.x] = acc;
    __syncthreads();
    if (threadIdx.x < 32) {
        float4 s = red[threadIdx.x];
        for (int w = 1; w < 8; w++) {
            float4 v = red[w * 32 + threadIdx.x];
            s.x += v.x; s.y += v.y; s.z += v.z; s.w += v.w;
        }
        float inv = 1.0f / fmaxf((float)(end - beg), 1.0f);
        ((float4*)p)[threadIdx.x] = make_float4(s.x * inv, s.y * inv, s.z * inv, s.w * inv);
    }
    __syncthreads();
    int f = threadIdx.x;
    if (f < H) {
        float a = b1[f];
        for (int k = 0; k < H; k++) a += p[k] * w1[k * H + f];
        hh[f] = a > 0.f ? a : 0.f;
    }
    __syncthreads();
    if (f < NC) {
        float l = b2[f];
        for (int k = 0; k < H; k++) l += hh[k] * w2[k * NC + f];
        lg[f] = l;
    }
    __syncthreads();
    if (f == 0) {
        float m = lg[0];
        for (int c = 1; c < NC; c++) m = m > lg[c] ? m : lg[c];
        float s = 0.f;
        for (int c = 0; c < NC; c++) s += expf(lg[c] - m);
        lsred = m + logf(s);
    }
    __syncthreads();
    if (f < NC) out[g * NC + f] = lg[f] - lsred;
}

extern "C" void kernel_launch(void* const* d_in, const int* in_sizes, int n_in,
                              void* d_out, int out_size, void* d_ws, size_t ws_size,
                              hipStream_t stream) {
    const float* x     = (const float*)d_in[0];
    const int*   ei    = (const int*)d_in[1];
    const int*   srcp  = ei;
    const int*   dstp  = ei + NE;
    const int*   batch = (const int*)d_in[2];
    const float* W[3]  = {(const float*)d_in[3],  (const float*)d_in[7],  (const float*)d_in[11]};
    const float* b[3]  = {(const float*)d_in[4],  (const float*)d_in[8],  (const float*)d_in[12]};
    const float* gm[3] = {(const float*)d_in[5],  (const float*)d_in[9],  (const float*)d_in[13]};
    const float* bt[3] = {(const float*)d_in[6],  (const float*)d_in[10], (const float*)d_in[14]};
    const float* w1 = (const float*)d_in[15];
    const float* b1 = (const float*)d_in[16];
    const float* w2 = (const float*)d_in[17];
    const float* b2 = (const float*)d_in[18];
    float* out = (float*)d_out;

    float* ws        = (float*)d_ws;
    float* dis       = ws;                          // 100000
    int*   rowptr    = (int*)(ws + 100000);         // 100001 (pad to 100004)
    int*   bcnt      = (int*)(ws + 200004);         // 98 (pad 128)
    int*   bbase     = (int*)(ws + 200132);         // 98 (pad 124)
    int*   gstart    = (int*)(ws + 200256);         // 101 (pad 108)
    float* ssbuf     = ws + 200364;                 // 768
    float* sp        = ws + 201132;                 // 131072 (stats partials)
    _Float16* wt     = (_Float16*)(ws + 332204);    // 3*16384 halves = 24576 floats
    int*   col       = (int*)(ws + 356780);         // NE
    int2*  staging   = (int2*)(ws + 1956780);       // NB*CAP int2 = 3612672 floats
    _Float16* aggh   = (_Float16*)(ws + 5569452);   // NN*H f16 = 6400000 floats
    unsigned char* hb = (unsigned char*)(ws + 11969452);  // NN*H fp8 = 3200000 floats

    hipMemsetAsync(bcnt, 0, NB * sizeof(int), stream);
    k_bucket1<<<(NE + 8191) / 8192, 256, 0, stream>>>(srcp, dstp, bcnt, staging);
    k_bprefix<<<2, 128, 0, stream>>>(bcnt, bbase, rowptr, batch, gstart);
    k_bucket2<<<NB, 256, 0, stream>>>(staging, bcnt, bbase, rowptr, dis, col);
    k_prepw3<<<192, 256, 0, stream>>>(W[0], W[1], W[2], wt);

    const float* ss_prev = nullptr;
    for (int l = 0; l < 3; l++) {
        float* ss = ssbuf + l * 256;
        k_gemm<<<(NN + 63) / 64, 256, 0, stream>>>(l == 0 ? x : nullptr,
                                                   l == 0 ? nullptr : aggh,
                                                   ss_prev, wt + l * 16384, dis, hb);
        k_agg<<<NN / 8, 256, 0, stream>>>(hb, rowptr, col, dis, b[l], aggh);
        k_stats_a<<<512, 128, 0, stream>>>(aggh, sp);
        k_stats_bss<<<1, 256, 0, stream>>>(sp, gm[l], bt[l], ss);
        ss_prev = ss;
    }

    k_poolhead<<<NG, 256, 0, stream>>>(aggh, ssbuf + 2 * 256, gstart, w1, b1, w2, b2, out);
}

// Round 11
// 568.188 us; speedup vs baseline: 2.0221x; 1.2306x over previous
//
#include <hip/hip_runtime.h>
#include <hip/hip_fp8.h>
#include <math.h>

constexpr int NN = 100000;   // nodes
constexpr int NE = 1600000;  // edges
constexpr int H  = 128;      // feat/hidden
constexpr int NG = 100;      // graphs
constexpr int NC = 10;       // classes
constexpr int NB = 98;       // CSR buckets (dst >> 10)
constexpr int CAP = 18432;   // per-bucket staging capacity (mean 16327, +16 sigma)
constexpr int NSLOT = 256;   // BN stats partial slots

typedef _Float16 half8 __attribute__((ext_vector_type(8)));
typedef _Float16 half4 __attribute__((ext_vector_type(4)));
typedef float    f32x4 __attribute__((ext_vector_type(4)));
typedef float    f32x2 __attribute__((ext_vector_type(2)));

// ---- fp8 e4m3 (OCP) helpers ----
static __device__ __forceinline__ unsigned char ftofp8(float f) {
#if __has_builtin(__builtin_amdgcn_cvt_pk_fp8_f32)
    int r = __builtin_amdgcn_cvt_pk_fp8_f32(f, f, 0, false);
    return (unsigned char)(r & 0xff);
#else
    __hip_fp8_e4m3 v(f);
    unsigned char b; __builtin_memcpy(&b, &v, 1); return b;
#endif
}

static __device__ __forceinline__ float4 fp8x4tof(unsigned int u) {
#if __has_builtin(__builtin_amdgcn_cvt_pk_f32_fp8)
    f32x2 lo = __builtin_amdgcn_cvt_pk_f32_fp8(u, false);
    f32x2 hi = __builtin_amdgcn_cvt_pk_f32_fp8(u, true);
    return make_float4(lo.x, lo.y, hi.x, hi.y);
#else
    float r[4];
    #pragma unroll
    for (int i = 0; i < 4; i++) {
        unsigned char b = (u >> (8 * i)) & 0xff;
        __hip_fp8_e4m3 v; __builtin_memcpy(&v, &b, 1); r[i] = (float)v;
    }
    return make_float4(r[0], r[1], r[2], r[3]);
#endif
}

// ---------------- CSR build pass 1: bin packed edges into fixed-CAP dst-bucket regions ----------------
// packed edge: (src << 10) | (dst & 1023)   [src < 2^17, bucket-local dst < 2^10]
__global__ __launch_bounds__(256) void k_bucket1(const int* __restrict__ src,
                                                 const int* __restrict__ dst,
                                                 int* __restrict__ bcnt,
                                                 unsigned int* __restrict__ staging) {
    __shared__ int hist[NB];
    __shared__ int base[NB];
    int tid = threadIdx.x;
    int chunk0 = blockIdx.x * 8192;
    if (tid < NB) hist[tid] = 0;
    __syncthreads();
    for (int i = tid; i < 8192; i += 256) {
        int e = chunk0 + i;
        if (e < NE) atomicAdd(&hist[dst[e] >> 10], 1);
    }
    __syncthreads();
    if (tid < NB) { base[tid] = atomicAdd(&bcnt[tid], hist[tid]); hist[tid] = 0; }
    __syncthreads();
    for (int i = tid; i < 8192; i += 256) {
        int e = chunk0 + i;
        if (e < NE) {
            int d = dst[e];
            int bk = d >> 10;
            int off = base[bk] + atomicAdd(&hist[bk], 1);
            if (off < CAP)
                staging[(size_t)bk * CAP + off] = ((unsigned)src[e] << 10) | (unsigned)(d & 1023);
        }
    }
}

// ---------------- bucket prefix (block 0) + graph boundaries (block 1) ----------------
__global__ void k_bprefix(const int* __restrict__ bcnt, int* __restrict__ bbase,
                          int* __restrict__ rowptr,
                          const int* __restrict__ batch, int* __restrict__ gstart) {
    if (blockIdx.x == 0) {
        if (threadIdx.x == 0) {
            int run = 0;
            for (int i = 0; i < NB; i++) { bbase[i] = run; run += bcnt[i]; }
            rowptr[NN] = NE;
        }
    } else {
        int g = threadIdx.x;
        if (g > NG) return;
        if (g == NG) { gstart[g] = NN; return; }
        int lo = 0, hi = NN;
        while (lo < hi) { int mid = (lo + hi) >> 1; if (batch[mid] < g) lo = mid + 1; else hi = mid; }
        gstart[g] = lo;
    }
}

// ---------------- CSR build pass 2: per-bucket deg/rowptr/dis + col scatter, all in LDS ----------------
__global__ __launch_bounds__(256) void k_bucket2(const unsigned int* __restrict__ staging,
                                                 const int* __restrict__ bcnt,
                                                 const int* __restrict__ bbase,
                                                 int* __restrict__ rowptr,
                                                 float* __restrict__ dis,
                                                 int* __restrict__ col) {
    __shared__ int degl[1024];
    __shared__ int cur[1024];
    __shared__ int tsum[256];
    int b = blockIdx.x, tid = threadIdx.x;
    int n0 = b << 10;
    int cnt = bcnt[b];
    int base = bbase[b];
    const unsigned int* st = staging + (size_t)b * CAP;
    ((int4*)degl)[tid] = make_int4(0, 0, 0, 0);
    __syncthreads();
    for (int i = tid; i < cnt; i += 256) atomicAdd(&degl[st[i] & 1023], 1);
    __syncthreads();
    int v[4], s = 0;
    #pragma unroll
    for (int k = 0; k < 4; k++) { v[k] = degl[tid * 4 + k]; s += v[k]; }
    tsum[tid] = s;
    __syncthreads();
    for (int off = 1; off < 256; off <<= 1) {
        int t = (tid >= off) ? tsum[tid - off] : 0;
        __syncthreads();
        tsum[tid] += t;
        __syncthreads();
    }
    int run = (tid == 0) ? 0 : tsum[tid - 1];
    #pragma unroll
    for (int k = 0; k < 4; k++) {
        int i = tid * 4 + k, node = n0 + i;
        if (node < NN) {
            rowptr[node] = base + run;
            cur[i] = run;
            dis[node] = rsqrtf((float)v[k] + 1.0f);
        }
        run += v[k];
    }
    __syncthreads();
    for (int i = tid; i < cnt; i += 256) {
        unsigned int e = st[i];
        int pos = atomicAdd(&cur[e & 1023], 1);
        col[base + pos] = (int)(e >> 10);
    }
}

// ---------------- W -> Wt (transposed, f16), all 3 layers, one dispatch ----------------
__global__ void k_prepw3(const float* __restrict__ W0, const float* __restrict__ W1,
                         const float* __restrict__ W2, _Float16* __restrict__ Wt) {
    int gi = blockIdx.x * 256 + threadIdx.x;  // 3 * 16384
    int l = gi >> 14, idx = gi & 16383;
    const float* W = (l == 0) ? W0 : (l == 1) ? W1 : W2;
    int n = idx >> 7, k = idx & 127;
    Wt[gi] = (_Float16)W[k * 128 + n];
}

// ---------------- MFMA GEMM: Y_fp8 = (relu(X*scale+shift) @ W) * dis[row] ----------------
__global__ __launch_bounds__(256) void k_gemm(const float* __restrict__ Xf,
                                              const _Float16* __restrict__ Xh,
                                              const float* __restrict__ ss,
                                              const _Float16* __restrict__ Wt,
                                              const float* __restrict__ dis,
                                              unsigned char* __restrict__ Y) {
    __shared__ _Float16 Wl[128][136];
    __shared__ _Float16 Xl[64][136];
    int tid = threadIdx.x;
    int row0 = blockIdx.x * 64;

    #pragma unroll
    for (int p = 0; p < 8; p++) {
        int idx = p * 2048 + tid * 8;
        int r = idx >> 7, c = idx & 127;
        *(uint4*)&Wl[r][c] = ((const uint4*)Wt)[idx >> 3];
    }
    if (Xh) {
        #pragma unroll
        for (int p = 0; p < 4; p++) {
            int idx = p * 2048 + tid * 8;
            int r = idx >> 7, c = idx & 127;
            int gr = row0 + r;
            half8 hv = {};
            if (gr < NN) hv = *(const half8*)&Xh[(size_t)gr * H + c];
            float4 sc0 = ((const float4*)ss)[c >> 2];
            float4 sc1 = ((const float4*)ss)[(c >> 2) + 1];
            float4 sh0 = ((const float4*)(ss + 128))[c >> 2];
            float4 sh1 = ((const float4*)(ss + 128))[(c >> 2) + 1];
            half8 o;
            o[0] = (_Float16)fmaxf((float)hv[0] * sc0.x + sh0.x, 0.f);
            o[1] = (_Float16)fmaxf((float)hv[1] * sc0.y + sh0.y, 0.f);
            o[2] = (_Float16)fmaxf((float)hv[2] * sc0.z + sh0.z, 0.f);
            o[3] = (_Float16)fmaxf((float)hv[3] * sc0.w + sh0.w, 0.f);
            o[4] = (_Float16)fmaxf((float)hv[4] * sc1.x + sh1.x, 0.f);
            o[5] = (_Float16)fmaxf((float)hv[5] * sc1.y + sh1.y, 0.f);
            o[6] = (_Float16)fmaxf((float)hv[6] * sc1.z + sh1.z, 0.f);
            o[7] = (_Float16)fmaxf((float)hv[7] * sc1.w + sh1.w, 0.f);
            *(half8*)&Xl[r][c] = o;
        }
    } else {
        #pragma unroll
        for (int p = 0; p < 8; p++) {
            int idx = p * 1024 + tid * 4;
            int r = idx >> 7, c = idx & 127;
            int gr = row0 + r;
            float4 v = make_float4(0.f, 0.f, 0.f, 0.f);
            if (gr < NN) v = *(const float4*)&Xf[(size_t)gr * H + c];
            half4 hv = {(_Float16)v.x, (_Float16)v.y, (_Float16)v.z, (_Float16)v.w};
            *(half4*)&Xl[r][c] = hv;
        }
    }
    __syncthreads();

    int wave = tid >> 6;
    int lane = tid & 63;
    int m = lane & 15;
    int quad = lane >> 4;

    half8 afrag[4];
    #pragma unroll
    for (int kc = 0; kc < 4; kc++)
        afrag[kc] = *(const half8*)&Xl[wave * 16 + m][kc * 32 + quad * 8];

    f32x4 acc[8];
    #pragma unroll
    for (int nt = 0; nt < 8; nt++) acc[nt] = (f32x4){0.f, 0.f, 0.f, 0.f};

    #pragma unroll
    for (int kc = 0; kc < 4; kc++) {
        #pragma unroll
        for (int nt = 0; nt < 8; nt++) {
            half8 b = *(const half8*)&Wl[nt * 16 + m][kc * 32 + quad * 8];
            acc[nt] = __builtin_amdgcn_mfma_f32_16x16x32_f16(afrag[kc], b, acc[nt], 0, 0, 0);
        }
    }

    float dv[4];
    #pragma unroll
    for (int r = 0; r < 4; r++) {
        int gr = row0 + wave * 16 + quad * 4 + r;
        dv[r] = (gr < NN) ? dis[gr] : 0.f;
    }
    #pragma unroll
    for (int nt = 0; nt < 8; nt++) {
        int c = nt * 16 + m;
        #pragma unroll
        for (int r = 0; r < 4; r++) {
            int gr = row0 + wave * 16 + quad * 4 + r;
            if (gr < NN) Y[(size_t)gr * H + c] = ftofp8(acc[nt][r] * dv[r]);
        }
    }
}

// ---------------- gather aggregate + fused BN stats partials ----------------
// One node per 64-lane wave: 8 feature-lanes (dwordx4 = 16 feats) x 8 edge sub-streams.
// out = dis[d]*(h'[d] + sum h'[col]) + bias; h' fp8 pre-scaled by dis.
__global__ __launch_bounds__(256) void k_agg(const unsigned char* __restrict__ hs,
                                             const int* __restrict__ rowptr,
                                             const int* __restrict__ col,
                                             const float* __restrict__ dis,
                                             const float* __restrict__ bias,
                                             _Float16* __restrict__ out,
                                             float* __restrict__ sp) {
    int wv = threadIdx.x >> 6;            // 0..3
    int node = blockIdx.x * 4 + wv;
    int lane = threadIdx.x & 63;
    int fl = lane & 7;     // feature slice: feats 16*fl .. 16*fl+15
    int sub = lane >> 3;   // edge sub-stream 0..7
    int beg = rowptr[node], end = rowptr[node + 1];
    float dd = dis[node];
    const uint4* h16 = (const uint4*)hs;  // 8 uint4 per 128B row

    float acc[16];
    #pragma unroll
    for (int k = 0; k < 16; k++) acc[k] = 0.f;
    if (sub == 0) {
        uint4 w = h16[(size_t)node * 8 + fl];
        float4 a0 = fp8x4tof(w.x), a1 = fp8x4tof(w.y), a2 = fp8x4tof(w.z), a3 = fp8x4tof(w.w);
        acc[0] = a0.x; acc[1] = a0.y; acc[2] = a0.z; acc[3] = a0.w;
        acc[4] = a1.x; acc[5] = a1.y; acc[6] = a1.z; acc[7] = a1.w;
        acc[8] = a2.x; acc[9] = a2.y; acc[10] = a2.z; acc[11] = a2.w;
        acc[12] = a3.x; acc[13] = a3.y; acc[14] = a3.z; acc[15] = a3.w;
    }

    #define ACCUM(W) { \
        float4 t0 = fp8x4tof((W).x), t1 = fp8x4tof((W).y), t2 = fp8x4tof((W).z), t3 = fp8x4tof((W).w); \
        acc[0] += t0.x; acc[1] += t0.y; acc[2] += t0.z; acc[3] += t0.w; \
        acc[4] += t1.x; acc[5] += t1.y; acc[6] += t1.z; acc[7] += t1.w; \
        acc[8] += t2.x; acc[9] += t2.y; acc[10] += t2.z; acc[11] += t2.w; \
        acc[12] += t3.x; acc[13] += t3.y; acc[14] += t3.z; acc[15] += t3.w; }

    int j = beg + sub;
    for (; j + 8 < end; j += 16) {
        int c0 = col[j], c1 = col[j + 8];
        uint4 w0 = h16[(size_t)c0 * 8 + fl];
        uint4 w1 = h16[(size_t)c1 * 8 + fl];
        ACCUM(w0) ACCUM(w1)
    }
    for (; j < end; j += 8) {
        uint4 w = h16[(size_t)col[j] * 8 + fl];
        ACCUM(w)
    }
    #undef ACCUM

    // butterfly over the 8 sub-streams (lanes xor 8,16,32)
    #pragma unroll
    for (int k = 0; k < 16; k++) {
        acc[k] += __shfl_xor(acc[k], 8, 64);
        acc[k] += __shfl_xor(acc[k], 16, 64);
        acc[k] += __shfl_xor(acc[k], 32, 64);
    }

    float4 b0 = ((const float4*)bias)[fl * 4 + 0];
    float4 b1 = ((const float4*)bias)[fl * 4 + 1];
    float4 b2 = ((const float4*)bias)[fl * 4 + 2];
    float4 b3 = ((const float4*)bias)[fl * 4 + 3];
    float o[16];
    o[0]  = acc[0]  * dd + b0.x; o[1]  = acc[1]  * dd + b0.y;
    o[2]  = acc[2]  * dd + b0.z; o[3]  = acc[3]  * dd + b0.w;
    o[4]  = acc[4]  * dd + b1.x; o[5]  = acc[5]  * dd + b1.y;
    o[6]  = acc[6]  * dd + b1.z; o[7]  = acc[7]  * dd + b1.w;
    o[8]  = acc[8]  * dd + b2.x; o[9]  = acc[9]  * dd + b2.y;
    o[10] = acc[10] * dd + b2.z; o[11] = acc[11] * dd + b2.w;
    o[12] = acc[12] * dd + b3.x; o[13] = acc[13] * dd + b3.y;
    o[14] = acc[14] * dd + b3.z; o[15] = acc[15] * dd + b3.w;

    __shared__ float lsum[4][128];
    __shared__ float lsq[4][128];
    if (sub == 0) {
        half8 o0, o1;
        #pragma unroll
        for (int k = 0; k < 8; k++) { o0[k] = (_Float16)o[k]; o1[k] = (_Float16)o[k + 8]; }
        half8* orow = (half8*)(out + (size_t)node * H);
        orow[fl * 2] = o0;
        orow[fl * 2 + 1] = o1;
        #pragma unroll
        for (int k = 0; k < 16; k++) {
            lsum[wv][fl * 16 + k] = o[k];
            lsq[wv][fl * 16 + k] = o[k] * o[k];
        }
    }
    __syncthreads();
    int c = threadIdx.x & 127;
    int which = threadIdx.x >> 7;  // 0 = sum, 1 = sumsq
    float v = 0.f;
    #pragma unroll
    for (int w = 0; w < 4; w++) v += which ? lsq[w][c] : lsum[w][c];
    atomicAdd(&sp[(blockIdx.x & (NSLOT - 1)) * 256 + which * 128 + c], v);
}

// ---------------- BN stats final reduce + scale/shift (re-zeros sp for next layer) ----------------
__global__ __launch_bounds__(256) void k_stats_bss(float* __restrict__ sp,
                                                   const float* __restrict__ gamma,
                                                   const float* __restrict__ beta,
                                                   float* __restrict__ ss) {
    __shared__ float sums[256];
    int c = threadIdx.x;  // 256
    float a = 0.f;
    for (int i = 0; i < NSLOT; i++) { a += sp[i * 256 + c]; sp[i * 256 + c] = 0.f; }
    sums[c] = a;
    __syncthreads();
    if (c < 128) {
        float mean = sums[c] * (1.0f / NN);
        float var  = sums[128 + c] * (1.0f / NN) - mean * mean;
        float sc   = gamma[c] * rsqrtf(var + 1e-5f);
        ss[c] = sc;
        ss[128 + c] = beta[c] - mean * sc;
    }
}

// ---------------- fused mean pool (BN+ReLU) + MLP head + log_softmax ----------------
__global__ __launch_bounds__(256) void k_poolhead(const _Float16* __restrict__ x,
                                                  const float* __restrict__ ss,
                                                  const int* __restrict__ gstart,
                                                  const float* __restrict__ w1, const float* __restrict__ b1,
                                                  const float* __restrict__ w2, const float* __restrict__ b2,
                                                  float* __restrict__ out) {
    int g = blockIdx.x;
    int beg = gstart[g], end = gstart[g + 1];
    int lane = threadIdx.x & 31;
    int walker = threadIdx.x >> 5;
    const half4* x4 = (const half4*)x;
    float4 sc = ((const float4*)ss)[lane];
    float4 sh = ((const float4*)(ss + 128))[lane];
    float4 acc = make_float4(0.f, 0.f, 0.f, 0.f);
    for (int r = beg + walker; r < end; r += 8) {
        half4 v = x4[(size_t)r * 32 + lane];
        acc.x += fmaxf((float)v.x * sc.x + sh.x, 0.f);
        acc.y += fmaxf((float)v.y * sc.y + sh.y, 0.f);
        acc.z += fmaxf((float)v.z * sc.z + sh.z, 0.f);
        acc.w += fmaxf((float)v.w * sc.w + sh.w, 0.f);
    }
    __shared__ float4 red[256];
    __shared__ float p[H], hh[H], lg[NC], lsred;
    red[threadIdx.x] = acc;
    __syncthreads();
    if (threadIdx.x < 32) {
        float4 s = red[threadIdx.x];
        for (int w = 1; w < 8; w++) {
            float4 v = red[w * 32 + threadIdx.x];
            s.x += v.x; s.y += v.y; s.z += v.z; s.w += v.w;
        }
        float inv = 1.0f / fmaxf((float)(end - beg), 1.0f);
        ((float4*)p)[threadIdx.x] = make_float4(s.x * inv, s.y * inv, s.z * inv, s.w * inv);
    }
    __syncthreads();
    int f = threadIdx.x;
    if (f < H) {
        float a = b1[f];
        for (int k = 0; k < H; k++) a += p[k] * w1[k * H + f];
        hh[f] = a > 0.f ? a : 0.f;
    }
    __syncthreads();
    if (f < NC) {
        float l = b2[f];
        for (int k = 0; k < H; k++) l += hh[k] * w2[k * NC + f];
        lg[f] = l;
    }
    __syncthreads();
    if (f == 0) {
        float m = lg[0];
        for (int c = 1; c < NC; c++) m = m > lg[c] ? m : lg[c];
        float s = 0.f;
        for (int c = 0; c < NC; c++) s += expf(lg[c] - m);
        lsred = m + logf(s);
    }
    __syncthreads();
    if (f < NC) out[g * NC + f] = lg[f] - lsred;
}

extern "C" void kernel_launch(void* const* d_in, const int* in_sizes, int n_in,
                              void* d_out, int out_size, void* d_ws, size_t ws_size,
                              hipStream_t stream) {
    const float* x     = (const float*)d_in[0];
    const int*   ei    = (const int*)d_in[1];
    const int*   srcp  = ei;
    const int*   dstp  = ei + NE;
    const int*   batch = (const int*)d_in[2];
    const float* W[3]  = {(const float*)d_in[3],  (const float*)d_in[7],  (const float*)d_in[11]};
    const float* b[3]  = {(const float*)d_in[4],  (const float*)d_in[8],  (const float*)d_in[12]};
    const float* gm[3] = {(const float*)d_in[5],  (const float*)d_in[9],  (const float*)d_in[13]};
    const float* bt[3] = {(const float*)d_in[6],  (const float*)d_in[10], (const float*)d_in[14]};
    const float* w1 = (const float*)d_in[15];
    const float* b1 = (const float*)d_in[16];
    const float* w2 = (const float*)d_in[17];
    const float* b2 = (const float*)d_in[18];
    float* out = (float*)d_out;

    float* ws        = (float*)d_ws;
    float* dis       = ws;                          // 100000
    int*   rowptr    = (int*)(ws + 100000);         // 100001 (pad 100004)
    int*   bcnt      = (int*)(ws + 200004);         // 98 (pad 128)
    int*   bbase     = (int*)(ws + 200132);         // 98 (pad 128)
    int*   gstart    = (int*)(ws + 200260);         // 101 (pad 108)
    float* ssbuf     = ws + 200368;                 // 768
    float* sp        = ws + 201136;                 // NSLOT*256 = 65536
    _Float16* wt     = (_Float16*)(ws + 266672);    // 3*16384 halves = 24576 floats
    int*   col       = (int*)(ws + 291248);         // NE
    unsigned int* staging = (unsigned int*)(ws + 1891248);  // NB*CAP = 1806336
    _Float16* aggh   = (_Float16*)(ws + 3697584);   // NN*H f16 = 6400000 floats
    unsigned char* hb = (unsigned char*)(ws + 10097584);  // NN*H fp8 = 3200000 floats

    hipMemsetAsync(bcnt, 0, NB * sizeof(int), stream);
    hipMemsetAsync(sp, 0, NSLOT * 256 * sizeof(float), stream);
    k_bucket1<<<(NE + 8191) / 8192, 256, 0, stream>>>(srcp, dstp, bcnt, staging);
    k_bprefix<<<2, 128, 0, stream>>>(bcnt, bbase, rowptr, batch, gstart);
    k_bucket2<<<NB, 256, 0, stream>>>(staging, bcnt, bbase, rowptr, dis, col);
    k_prepw3<<<192, 256, 0, stream>>>(W[0], W[1], W[2], wt);

    const float* ss_prev = nullptr;
    for (int l = 0; l < 3; l++) {
        float* ss = ssbuf + l * 256;
        k_gemm<<<(NN + 63) / 64, 256, 0, stream>>>(l == 0 ? x : nullptr,
                                                   l == 0 ? nullptr : aggh,
                                                   ss_prev, wt + l * 16384, dis, hb);
        k_agg<<<NN / 4, 256, 0, stream>>>(hb, rowptr, col, dis, b[l], aggh, sp);
        k_stats_bss<<<1, 256, 0, stream>>>(sp, gm[l], bt[l], ss);
        ss_prev = ss;
    }

    k_poolhead<<<NG, 256, 0, stream>>>(aggh, ssbuf + 2 * 256, gstart, w1, b1, w2, b2, out);
}